// Round 1
// baseline (13.093 us; speedup 1.0000x reference)
//
#include <hip/hip_runtime.h>
#include <math.h>

#define NQ 4
#define PPD 63          // (128-4)/2 + 1
#define BATCH 64
#define TOTAL (BATCH*PPD*PPD)   // 254016 patches

struct cplx { float x, y; };

__device__ __forceinline__ cplx cmul(cplx a, cplx b) {
    return { a.x*b.x - a.y*b.y, a.x*b.y + a.y*b.x };
}

// RZ(theta): v0 *= e^{-i theta/2}, v1 *= e^{+i theta/2}
__device__ __forceinline__ void apply_rz(cplx& v0, cplx& v1, float th) {
    float s, c;
    __sincosf(0.5f * th, &s, &c);
    cplx n0 = { v0.x*c + v0.y*s, v0.y*c - v0.x*s };
    cplx n1 = { v1.x*c - v1.y*s, v1.y*c + v1.x*s };
    v0 = n0; v1 = n1;
}

// RY(theta): [[c,-s],[s,c]] (real), applied to both re and im
__device__ __forceinline__ void apply_ry(cplx& v0, cplx& v1, float th) {
    float s, c;
    __sincosf(0.5f * th, &s, &c);
    cplx n0 = { c*v0.x - s*v1.x, c*v0.y - s*v1.y };
    cplx n1 = { s*v0.x + c*v1.x, s*v0.y + c*v1.y };
    v0 = n0; v1 = n1;
}

__global__ void __launch_bounds__(256)
quanv_kernel(const float* __restrict__ X, const float* __restrict__ W,
             float* __restrict__ out) {
    int tid = blockIdx.x * 256 + threadIdx.x;
    if (tid >= TOTAL) return;

    int b  = tid / (PPD * PPD);
    int rc = tid - b * (PPD * PPD);
    int r  = rc / PPD;
    int c  = rc - r * PPD;

    // ---- gather 4x4 patch: th[ki*4+kj] = X[b,0, 2r+ki, 2c+kj] ----
    const float* xp = X + b * (128 * 128) + (r * 2) * 128 + (c * 2);
    float th[16];
    #pragma unroll
    for (int i = 0; i < 4; ++i) {
        #pragma unroll
        for (int j = 0; j < 4; ++j)
            th[i * 4 + j] = xp[i * 128 + j];
    }

    // ---- per-qubit 2-vector: |0> -> H -> data gates ----
    // wire q occupies bit (3-q) of the flattened index (ref flatten order)
    const float is2 = 0.70710678118654752440f;
    cplx v[NQ][2];
    #pragma unroll
    for (int q = 0; q < NQ; ++q) {
        v[q][0] = { is2, 0.f };
        v[q][1] = { is2, 0.f };
    }
    #pragma unroll
    for (int q = 0; q < 3; ++q) {           // qubits 0..2: RZ,RY,RZ,RY,RZ
        apply_rz(v[q][0], v[q][1], th[q * 5 + 0]);
        apply_ry(v[q][0], v[q][1], th[q * 5 + 1]);
        apply_rz(v[q][0], v[q][1], th[q * 5 + 2]);
        apply_ry(v[q][0], v[q][1], th[q * 5 + 3]);
        apply_rz(v[q][0], v[q][1], th[q * 5 + 4]);
    }
    apply_rz(v[3][0], v[3][1], th[15]);     // qubit 3: only RZ(th15)

    // ---- tensor product -> 16 amplitudes ----
    cplx p01[4], p23[4];
    #pragma unroll
    for (int i = 0; i < 2; ++i)
        #pragma unroll
        for (int j = 0; j < 2; ++j) {
            p01[i * 2 + j] = cmul(v[0][i], v[1][j]);
            p23[i * 2 + j] = cmul(v[2][i], v[3][j]);
        }
    cplx a[16];
    #pragma unroll
    for (int k = 0; k < 16; ++k)
        a[k] = cmul(p01[k >> 2], p23[k & 3]);

    // ---- CRZ layer (diagonal): phi_k = sum_i bit(i) * w_i * (bit(i+1)? .5 : -.5)
    float hw0 = 0.5f * W[0], hw1 = 0.5f * W[1], hw2 = 0.5f * W[2], hw3 = 0.5f * W[3];
    float hw[4] = { hw0, hw1, hw2, hw3 };
    #pragma unroll
    for (int k = 0; k < 16; ++k) {
        float phi = 0.f;
        #pragma unroll
        for (int i = 0; i < 4; ++i) {
            const int bi = (k >> (3 - i)) & 1;                 // ctrl bit
            const int bt = (k >> (3 - ((i + 1) & 3))) & 1;     // tgt bit
            if (bi) phi += bt ? hw[i] : -hw[i];
        }
        float s, cph;
        __sincosf(phi, &s, &cph);
        a[k] = cmul(a[k], { cph, s });
    }

    // ---- final RY(w[4+q]) on each qubit q ----
    #pragma unroll
    for (int q = 0; q < NQ; ++q) {
        float s, cc;
        __sincosf(0.5f * W[4 + q], &s, &cc);
        const int mask = 1 << (3 - q);
        #pragma unroll
        for (int k = 0; k < 16; ++k) {
            if (k & mask) continue;
            const int k1 = k | mask;
            cplx a0 = a[k], a1 = a[k1];
            a[k]  = { cc*a0.x - s*a1.x, cc*a0.y - s*a1.y };
            a[k1] = { s*a0.x + cc*a1.x, s*a0.y + cc*a1.y };
        }
    }

    // ---- measure Z on each qubit ----
    float p[16];
    #pragma unroll
    for (int k = 0; k < 16; ++k)
        p[k] = a[k].x*a[k].x + a[k].y*a[k].y;

    float zq[NQ];
    #pragma unroll
    for (int q = 0; q < NQ; ++q) {
        const int mask = 1 << (3 - q);
        float acc = 0.f;
        #pragma unroll
        for (int k = 0; k < 16; ++k)
            acc += (k & mask) ? -p[k] : p[k];
        zq[q] = acc;
    }

    // out flat index = b*15876 + (r*63+c)*4 + q  -> one aligned float4
    float4* o = reinterpret_cast<float4*>(out) + tid;
    *o = make_float4(zq[0], zq[1], zq[2], zq[3]);
}

extern "C" void kernel_launch(void* const* d_in, const int* in_sizes, int n_in,
                              void* d_out, int out_size, void* d_ws, size_t ws_size,
                              hipStream_t stream) {
    const float* X = (const float*)d_in[0];   // (64,1,128,128) f32
    const float* W = (const float*)d_in[1];   // (1,8) f32
    float* out = (float*)d_out;               // (64,4,63,63) f32

    const int blocks = (TOTAL + 255) / 256;   // 993
    quanv_kernel<<<dim3(blocks), dim3(256), 0, stream>>>(X, W, out);
}

// Round 2
// 10.753 us; speedup vs baseline: 1.2177x; 1.2177x over previous
//
#include <hip/hip_runtime.h>
#include <math.h>

#define PPD 63                   // (128-4)/2 + 1
#define TOTAL (64*PPD*PPD)       // 254016 patches

__global__ void __launch_bounds__(256)
quanv_kernel(const float* __restrict__ X, const float* __restrict__ W,
             float* __restrict__ out) {
    // Uniform (weight-only) trig, computed once per block, broadcast via LDS.
    __shared__ float2 crz[16];   // (cos, sin) of CRZ diagonal phase per basis state
    __shared__ float2 ryw[4];    // (cos(w)*1/16, sin(w)*1/8) for measurement fold

    const int lt = threadIdx.x;
    if (lt < 16) {
        float phi = 0.f;
        #pragma unroll
        for (int i = 0; i < 4; ++i) {
            const int bi = (lt >> (3 - i)) & 1;              // ctrl bit
            const int bt = (lt >> (3 - ((i + 1) & 3))) & 1;  // tgt bit
            if (bi) phi += (bt ? 0.5f : -0.5f) * W[i];
        }
        float s, c; __sincosf(phi, &s, &c);
        crz[lt] = make_float2(c, s);
    } else if (lt < 20) {
        const int q = lt - 16;
        float s, c; __sincosf(W[4 + q], &s, &c);             // FULL angle
        ryw[q] = make_float2(0.0625f * c, 0.125f * s);       // 1/16·cos, 2/16·sin
    }
    __syncthreads();

    const int tid = blockIdx.x * 256 + lt;
    if (tid >= TOTAL) return;

    const int b  = tid / (PPD * PPD);
    const int rc = tid - b * (PPD * PPD);
    const int r  = rc / PPD;
    const int c  = rc - r * PPD;

    // ---- gather 4x4 patch (rows are 8B-aligned: even element offset) ----
    const float2* xp = reinterpret_cast<const float2*>(
        X + b * (128 * 128) + (r * 2) * 128 + (c * 2));
    float th[16];
    #pragma unroll
    for (int i = 0; i < 4; ++i) {
        const float2 lo = xp[i * 64];
        const float2 hi = xp[i * 64 + 1];
        th[i*4+0] = lo.x; th[i*4+1] = lo.y;
        th[i*4+2] = hi.x; th[i*4+3] = hi.y;
    }

    // ---- per-qubit chains, phase-factored: RZ(t) ~ diag(1, e^{it}) ----
    // start after H: (1,1) (norm deferred); qubit q sits at bit (3-q)
    float vx[3][2], vy[3][2];
    #pragma unroll
    for (int q = 0; q < 3; ++q) {
        float s0,c0,s1,c1,s2,c2,s3,c3,s4,c4;
        __sincosf(       th[q*5+0], &s0, &c0);   // RZ full angle
        __sincosf(0.5f * th[q*5+1], &s1, &c1);   // RY half angle
        __sincosf(       th[q*5+2], &s2, &c2);
        __sincosf(0.5f * th[q*5+3], &s3, &c3);
        __sincosf(       th[q*5+4], &s4, &c4);
        // v0=(1,0), v1=(c0,s0); apply RY(t1)
        const float v0x = c1 - s1*c0, v0y = -s1*s0;
        const float v1x = s1 + c1*c0, v1y =  c1*s0;
        // RZ(t2) on v1
        const float w1x = v1x*c2 - v1y*s2, w1y = v1x*s2 + v1y*c2;
        // RY(t3)
        const float n0x = c3*v0x - s3*w1x, n0y = c3*v0y - s3*w1y;
        const float n1x = s3*v0x + c3*w1x, n1y = s3*v0y + c3*w1y;
        // RZ(t4) on v1
        vx[q][0] = n0x;               vy[q][0] = n0y;
        vx[q][1] = n1x*c4 - n1y*s4;   vy[q][1] = n1x*s4 + n1y*c4;
    }
    float ds_, dc_;
    __sincosf(th[15], &ds_, &dc_);   // qubit 3: (1, e^{i th15})

    // ---- tensor product ----
    float px[4], py[4];              // qubits 0,1
    #pragma unroll
    for (int i = 0; i < 2; ++i)
        #pragma unroll
        for (int j = 0; j < 2; ++j) {
            px[i*2+j] = vx[0][i]*vx[1][j] - vy[0][i]*vy[1][j];
            py[i*2+j] = vx[0][i]*vy[1][j] + vy[0][i]*vx[1][j];
        }
    float qx[4], qy[4];              // qubits 2,3 (qubit-3 v0 = (1,0))
    #pragma unroll
    for (int i = 0; i < 2; ++i) {
        qx[i*2+0] = vx[2][i];
        qy[i*2+0] = vy[2][i];
        qx[i*2+1] = vx[2][i]*dc_ - vy[2][i]*ds_;
        qy[i*2+1] = vx[2][i]*ds_ + vy[2][i]*dc_;
    }

    // ---- 16 amplitudes with CRZ diagonal phase folded in ----
    float ax[16], ay[16];
    #pragma unroll
    for (int k = 0; k < 16; ++k) {
        const float tx = px[k>>2]*qx[k&3] - py[k>>2]*qy[k&3];
        const float ty = px[k>>2]*qy[k&3] + py[k>>2]*qx[k&3];
        const float2 t = crz[k];
        ax[k] = tx*t.x - ty*t.y;
        ay[k] = tx*t.y + ty*t.x;
    }

    // ---- measurement: z_q = cos(w)·<Z_q> - sin(w)·<X_q> (scales in ryw) ----
    float p[16];
    #pragma unroll
    for (int k = 0; k < 16; ++k) p[k] = ax[k]*ax[k] + ay[k]*ay[k];

    float z[4];
    #pragma unroll
    for (int q = 0; q < 4; ++q) {
        const int mask = 8 >> q;
        float zs = 0.f, xs = 0.f;
        #pragma unroll
        for (int k = 0; k < 16; ++k) {
            if (k & mask) continue;
            const int k1 = k | mask;
            zs += p[k] - p[k1];
            xs += ax[k]*ax[k1] + ay[k]*ay[k1];   // Re(conj(a0)·a1)
        }
        const float2 w = ryw[q];
        z[q] = w.x * zs - w.y * xs;
    }

    reinterpret_cast<float4*>(out)[tid] = make_float4(z[0], z[1], z[2], z[3]);
}

extern "C" void kernel_launch(void* const* d_in, const int* in_sizes, int n_in,
                              void* d_out, int out_size, void* d_ws, size_t ws_size,
                              hipStream_t stream) {
    const float* X = (const float*)d_in[0];   // (64,1,128,128) f32
    const float* W = (const float*)d_in[1];   // (1,8) f32
    float* out = (float*)d_out;               // (64,4,63,63) f32

    const int blocks = (TOTAL + 255) / 256;   // 993
    quanv_kernel<<<dim3(blocks), dim3(256), 0, stream>>>(X, W, out);
}

// Round 3
// 10.057 us; speedup vs baseline: 1.3019x; 1.0692x over previous
//
#include <hip/hip_runtime.h>
#include <math.h>

#define PPD 63                   // (128-4)/2 + 1
#define TOTAL (64*PPD*PPD)       // 254016 patches

__global__ void __launch_bounds__(256)
quanv_kernel(const float* __restrict__ X, const float* __restrict__ W,
             float* __restrict__ out) {
    // Weight-only (uniform) trig, once per block, broadcast via LDS.
    __shared__ float uA[4][2];   // cos(W[q]/2), 0.5*sin(W[q]/2)   (CRZ "A" factor)
    __shared__ float uB[4][2];   // cos(W[q]),   sin(W[q])         (CRZ "B" factor)
    __shared__ float uR[4][2];   // 0.5*cos(W[4+q]), 0.5*sin(W[4+q]) (final-RY fold)

    const int lt = threadIdx.x;
    if (lt < 4) {
        float s, c;
        __sincosf(0.5f * W[lt], &s, &c);
        uA[lt][0] = c;        uA[lt][1] = 0.5f * s;
        __sincosf(W[lt], &s, &c);
        uB[lt][0] = c;        uB[lt][1] = s;
        __sincosf(W[4 + lt], &s, &c);
        uR[lt][0] = 0.5f * c; uR[lt][1] = 0.5f * s;
    }
    __syncthreads();

    const int tid = blockIdx.x * 256 + lt;
    if (tid >= TOTAL) return;

    const int b  = tid / (PPD * PPD);
    const int rc = tid - b * (PPD * PPD);
    const int r  = rc / PPD;
    const int c  = rc - r * PPD;

    // ---- gather 4x4 patch (rows 8B-aligned: even element offset) ----
    const float2* xp = reinterpret_cast<const float2*>(
        X + b * (128 * 128) + (r * 2) * 128 + (c * 2));
    float th[16];
    #pragma unroll
    for (int i = 0; i < 4; ++i) {
        const float2 lo = xp[i * 64];
        const float2 hi = xp[i * 64 + 1];
        th[i*4+0] = lo.x; th[i*4+1] = lo.y;
        th[i*4+2] = hi.x; th[i*4+3] = hi.y;
    }

    // ---- per-qubit chains (phase-factored RZ ~ diag(1,e^{it})), raw norm^2 = 2 ----
    float p0[4], p1[4], dr[4], mr[4], mi[4];
    #pragma unroll
    for (int q = 0; q < 3; ++q) {           // qubits 0..2: RZ,RY,RZ,RY,RZ
        float s0,c0,s1,c1,s2,c2,s3,c3,s4,c4;
        __sincosf(       th[q*5+0], &s0, &c0);
        __sincosf(0.5f * th[q*5+1], &s1, &c1);
        __sincosf(       th[q*5+2], &s2, &c2);
        __sincosf(0.5f * th[q*5+3], &s3, &c3);
        __sincosf(       th[q*5+4], &s4, &c4);
        // start (1,0),(c0,s0); RY(t1)
        const float v0x = c1 - s1*c0, v0y = -s1*s0;
        const float v1x = s1 + c1*c0, v1y =  c1*s0;
        // RZ(t2) on v1
        const float w1x = v1x*c2 - v1y*s2, w1y = v1x*s2 + v1y*c2;
        // RY(t3)
        const float n0x = c3*v0x - s3*w1x, n0y = c3*v0y - s3*w1y;
        const float n1x = s3*v0x + c3*w1x, n1y = s3*v0y + c3*w1y;
        // RZ(t4) on v1 (phase only affects m via v1)
        const float f1x = n1x*c4 - n1y*s4, f1y = n1x*s4 + n1y*c4;
        // per-qubit raw stats
        const float P0 = n0x*n0x + n0y*n0y;
        const float P1 = f1x*f1x + f1y*f1y;
        p0[q] = P0; p1[q] = P1; dr[q] = P0 - P1;
        mr[q] = n0x*f1x + n0y*f1y;          // Re(conj(v0)*v1)
        mi[q] = n0x*f1y - n0y*f1x;          // Im(conj(v0)*v1)
    }
    {   // qubit 3: only RZ(th15): raw state (1, e^{i th}) -> closed-form stats
        float s, c; __sincosf(th[15], &s, &c);
        p0[3] = 1.f; p1[3] = 1.f; dr[3] = 0.f;
        mr[3] = c;   mi[3] = s;
    }

    // ---- z_q = 0.5cos(wry)*d_q - 0.5sin(wry)*Re[m_q * A_q * B_q] ----
    // A_q = (cos(w_q/2), -d_{q+1}*0.5sin(w_q/2));  B_q = P_{q-1,0} + P_{q-1,1} e^{i w_{q-1}}
    float z[4];
    #pragma unroll
    for (int q = 0; q < 4; ++q) {
        const int qn = (q + 1) & 3;          // A uses d of qubit q+1
        const int j  = (q + 3) & 3;          // B uses qubit q-1 and weight W[q-1]
        const float as_ = dr[qn] * uA[q][1];          // = -Im(A_q)
        const float br  = p0[j] + p1[j] * uB[j][0];
        const float bi  = p1[j] * uB[j][1];
        const float chw = uA[q][0];
        const float re  = mr[q]*chw + mi[q]*as_;      // Re(m*A)
        const float im  = mi[q]*chw - mr[q]*as_;      // Im(m*A)
        z[q] = uR[q][0]*dr[q] - uR[q][1]*(re*br - im*bi);
    }

    reinterpret_cast<float4*>(out)[tid] = make_float4(z[0], z[1], z[2], z[3]);
}

extern "C" void kernel_launch(void* const* d_in, const int* in_sizes, int n_in,
                              void* d_out, int out_size, void* d_ws, size_t ws_size,
                              hipStream_t stream) {
    const float* X = (const float*)d_in[0];   // (64,1,128,128) f32
    const float* W = (const float*)d_in[1];   // (1,8) f32
    float* out = (float*)d_out;               // (64,4,63,63) f32

    const int blocks = (TOTAL + 255) / 256;   // 993
    quanv_kernel<<<dim3(blocks), dim3(256), 0, stream>>>(X, W, out);
}